// Round 16
// baseline (20.764 us; speedup 1.0000x reference)
//
#include <hip/hip_runtime.h>
#include <stdint.h>

#define SEQ  8192
#define NB   128
#define MAXP 4096
#define NT   512
#define RED  4                     // blocks per sequence (grid = 512 = 2 blocks/CU)
#define NCH  256                   // 32-wide chunks per sequence

typedef int  i32x4 __attribute__((ext_vector_type(4)));   // native vec for nt-store

__device__ __forceinline__ bool haszero8(uint64_t v) {
    return ((v - 0x0101010101010101ULL) & ~v & 0x8080808080808080ULL) != 0ULL;
}
__device__ __forceinline__ bool distinct8(uint64_t w) {
    uint64_t r1 = (w >> 8)  | (w << 56);
    uint64_t r2 = (w >> 16) | (w << 48);
    uint64_t r3 = (w >> 24) | (w << 40);
    uint64_t r4 = (w >> 32) | (w << 32);
    return !(haszero8(w ^ r1) | haszero8(w ^ r2) | haszero8(w ^ r3) | haszero8(w ^ r4));
}
__device__ __forceinline__ uint32_t pack4(int4 v) {
    return (uint32_t)(v.x & 255) | ((uint32_t)(v.y & 255) << 8) |
           ((uint32_t)(v.z & 255) << 16) | ((uint32_t)(v.w & 255) << 24);
}
__device__ __forceinline__ uint32_t bsel16(uint4 f, uint32_t b) {
    uint32_t w01 = (b & 4u) ? f.y : f.x;
    uint32_t w23 = (b & 4u) ? f.w : f.z;
    uint32_t w   = (b & 8u) ? w23 : w01;
    return (w >> ((b & 3u) << 3)) & 255u;
}
// byte pack: {a.b2,a.b0,b.b2,b.b0} -> one word (exit-byte table)
__device__ __forceinline__ uint32_t packexit(uint32_t pa, uint32_t pb) {
#if __has_builtin(__builtin_amdgcn_perm)
    return __builtin_amdgcn_perm(pb, pa, 0x06040200u);
#else
    return (pa & 0xFFu) | (((pa >> 16) & 0xFFu) << 8) |
           ((pb & 0xFFu) << 16) | (((pb >> 16) & 0xFFu) << 24);
#endif
}
// r.byte[i] = g.byte[f.byte[i]]  (byte values in [0,16)) -- proven rounds 5-15
__device__ __forceinline__ uint4 comp16(uint4 g, uint4 f) {
    uint4 r;
#if __has_builtin(__builtin_amdgcn_perm)
    #define C16W(fw, out) do { \
        uint32_t sel = (fw) & 0x07070707u; \
        uint32_t lo = __builtin_amdgcn_perm(g.y, g.x, sel); \
        uint32_t hi = __builtin_amdgcn_perm(g.w, g.z, sel); \
        uint32_t m = ((fw) & 0x08080808u) >> 3; m = (m << 8) - m; \
        out = (lo & ~m) | (hi & m); } while (0)
    C16W(f.x, r.x); C16W(f.y, r.y); C16W(f.z, r.z); C16W(f.w, r.w);
    #undef C16W
#else
    #define C16B(fw, out) do { uint32_t o = 0; \
        o |= bsel16(g, (fw) & 15u); \
        o |= bsel16(g, ((fw) >> 8) & 15u) << 8; \
        o |= bsel16(g, ((fw) >> 16) & 15u) << 16; \
        o |= bsel16(g, ((fw) >> 24) & 15u) << 24; \
        out = o; } while (0)
    C16B(f.x, r.x); C16B(f.y, r.y); C16B(f.z, r.z); C16B(f.w, r.w);
    #undef C16B
#endif
    return r;
}

__global__ __launch_bounds__(NT) void ep_fused(const int* __restrict__ tokens,
                                               int* __restrict__ out) {
    __shared__ uint32_t tok32[2056];     // 8192 tokens u8-packed + 32B zero pad
    __shared__ uint32_t stopb[258];
    __shared__ uint32_t st16[NCH * 9];   // per chunk: st[0..15] packed (8 words, stride 9)
    __shared__ uint32_t exitf32[NCH * 4];
    __shared__ uint8_t  entry_s[NCH];
    __shared__ uint16_t pbase_s[NCH];
    __shared__ uint16_t starts_s[4100];
    __shared__ int S_s[2];               // 0: total P

    const int bx = blockIdx.x;
    const int b = bx >> 2, qc = bx & 3;  // sequence, emission quarter
    const int tid = threadIdx.x;

    // ---- A: coalesced load, pack tokens to u8 (proven) ----
    {
        const int4* t4 = (const int4*)(tokens + (size_t)b * SEQ);
        #pragma unroll
        for (int k = 0; k < 4; ++k) { int g = k * NT + tid; tok32[g] = pack4(t4[g]); }
        if (tid < 8) tok32[2048 + tid] = 0u;
        if (tid < 2) stopb[256 + tid] = 0u;
    }
    __syncthreads();                     // b1

    // ---- B: stop bits, 16 windows/thread (proven R12); pack pairs via shfl ----
    {
        const int base = tid * 4;
        uint64_t win = (uint64_t)tok32[base] | ((uint64_t)tok32[base + 1] << 32);
        uint32_t bits = 0;
        #pragma unroll
        for (int k = 0; k < 4; ++k) {
            uint32_t nx = tok32[base + 2 + k];
            #pragma unroll
            for (int m = 0; m < 4; ++m) {
                if (distinct8(win)) bits |= (1u << (k * 4 + m));
                win = (win >> 8) | ((uint64_t)(nx & 255u) << 56);
                nx >>= 8;
            }
        }
        if (tid == NT - 1) bits &= 0x1FFu;       // j <= SEQ-8 for the tail thread
        uint32_t other = (uint32_t)__shfl_xor((int)bits, 1);
        if ((tid & 1) == 0) stopb[tid >> 1] = (bits & 0xFFFFu) | (other << 16);
    }
    __syncthreads();                     // b2

    // ---- T: per-chunk backward DP, register sliding window (proven R12) ----
    if (tid < NCH) {
        const int c = tid;
        const uint64_t W = (uint64_t)stopb[c] | ((uint64_t)stopb[c + 1] << 32);
        const int gb = c * 32;
        uint32_t p0 = 0, p1 = 0, p2 = 0, p3 = 0, p4 = 0, p5 = 0, p6 = 0, p7 = 0;
        #pragma unroll
        for (int rel = 31; rel >= 0; --rel) {
            uint32_t win14 = (uint32_t)(W >> (rel + 2)) & 0x3FFFu;
            int sz = win14 ? (2 + __builtin_ctz(win14)) : min(16, SEQ - (gb + rel));
            int nxt = rel + sz;
            uint32_t stv;
            if (nxt >= 32) {
                stv = (uint32_t)(nxt - 32) | 0x100u;
            } else {
                int s = sz - 1;
                uint32_t q01 = (s & 2) ? p1 : p0;
                uint32_t q23 = (s & 2) ? p3 : p2;
                uint32_t q45 = (s & 2) ? p5 : p4;
                uint32_t q67 = (s & 2) ? p7 : p6;
                uint32_t qa  = (s & 4) ? q23 : q01;
                uint32_t qb  = (s & 4) ? q67 : q45;
                uint32_t q   = (s & 8) ? qb : qa;
                uint32_t sel = (s & 1) ? (q >> 16) : (q & 0xFFFFu);
                stv = sel + 0x100u;
            }
            p7 = (p7 << 16) | (p6 >> 16);
            p6 = (p6 << 16) | (p5 >> 16);
            p5 = (p5 << 16) | (p4 >> 16);
            p4 = (p4 << 16) | (p3 >> 16);
            p3 = (p3 << 16) | (p2 >> 16);
            p2 = (p2 << 16) | (p1 >> 16);
            p1 = (p1 << 16) | (p0 >> 16);
            p0 = (p0 << 16) | stv;
        }
        uint32_t* st = st16 + c * 9;
        st[0] = p0; st[1] = p1; st[2] = p2; st[3] = p3;
        st[4] = p4; st[5] = p5; st[6] = p6; st[7] = p7;
        exitf32[c * 4 + 0] = packexit(p0, p1);
        exitf32[c * 4 + 1] = packexit(p2, p3);
        exitf32[c * 4 + 2] = packexit(p4, p5);
        exitf32[c * 4 + 3] = packexit(p6, p7);
    }
    __syncthreads();                     // b3

    // ---- S: wave-0 mega-phase: fn scan -> entries, counts, pbases, P (proven) ----
    if (tid < 64) {
        const uint4* xf4 = (const uint4*)exitf32;
        uint4 f0 = xf4[tid * 4], f1 = xf4[tid * 4 + 1],
              f2 = xf4[tid * 4 + 2], f3 = xf4[tid * 4 + 3];
        uint4 g = comp16(f1, f0);
        g = comp16(f2, g);
        g = comp16(f3, g);
        #pragma unroll
        for (int d = 1; d < 64; d <<= 1) {
            uint4 o;
            o.x = (uint32_t)__shfl_up((int)g.x, d);
            o.y = (uint32_t)__shfl_up((int)g.y, d);
            o.z = (uint32_t)__shfl_up((int)g.z, d);
            o.w = (uint32_t)__shfl_up((int)g.w, d);
            if (tid >= d) g = comp16(g, o);
        }
        uint4 E;
        E.x = (uint32_t)__shfl_up((int)g.x, 1);
        E.y = (uint32_t)__shfl_up((int)g.y, 1);
        E.z = (uint32_t)__shfl_up((int)g.z, 1);
        E.w = (uint32_t)__shfl_up((int)g.w, 1);
        if (tid == 0) E = make_uint4(0x03020100u, 0x07060504u, 0x0B0A0908u, 0x0F0E0D0Cu);
        uint32_t e0 = E.x & 255u;
        uint32_t e1 = bsel16(f0, e0);
        uint32_t e2 = bsel16(f1, e1);
        uint32_t e3 = bsel16(f2, e2);
        entry_s[tid * 4 + 0] = (uint8_t)e0;
        entry_s[tid * 4 + 1] = (uint8_t)e1;
        entry_s[tid * 4 + 2] = (uint8_t)e2;
        entry_s[tid * 4 + 3] = (uint8_t)e3;
        uint32_t w0 = st16[(tid * 4 + 0) * 9 + (e0 >> 1)];
        uint32_t w1 = st16[(tid * 4 + 1) * 9 + (e1 >> 1)];
        uint32_t w2 = st16[(tid * 4 + 2) * 9 + (e2 >> 1)];
        uint32_t w3 = st16[(tid * 4 + 3) * 9 + (e3 >> 1)];
        int c0 = (int)(((w0 >> ((e0 & 1) * 16)) & 0xFFFFu) >> 8);
        int c1 = (int)(((w1 >> ((e1 & 1) * 16)) & 0xFFFFu) >> 8);
        int c2 = (int)(((w2 >> ((e2 & 1) * 16)) & 0xFFFFu) >> 8);
        int c3 = (int)(((w3 >> ((e3 & 1) * 16)) & 0xFFFFu) >> 8);
        int s = c0 + c1 + c2 + c3;
        int incl = s;
        #pragma unroll
        for (int d = 1; d < 64; d <<= 1) { int o = __shfl_up(incl, d); if (tid >= d) incl += o; }
        int excl = incl - s;
        pbase_s[tid * 4 + 0] = (uint16_t)excl;
        pbase_s[tid * 4 + 1] = (uint16_t)(excl + c0);
        pbase_s[tid * 4 + 2] = (uint16_t)(excl + c0 + c1);
        pbase_s[tid * 4 + 3] = (uint16_t)(excl + c0 + c1 + c2);
        if (tid == 63) S_s[0] = incl;    // total P
    }
    __syncthreads();                     // b4

    // ---- X: expand chunks via register walk + sentinel fill ----
    if (tid < NCH) {
        const int c = tid;
        const uint64_t W = (uint64_t)stopb[c] | ((uint64_t)stopb[c + 1] << 32);
        const int gb = c * 32;
        int pb = (int)pbase_s[c];
        int rel = (int)entry_s[c];
        while (rel < 32) {
            starts_s[pb++] = (uint16_t)(gb + rel);
            uint32_t win14 = (uint32_t)(W >> (rel + 2)) & 0x3FFFu;
            rel += win14 ? (2 + __builtin_ctz(win14)) : min(16, SEQ - (gb + rel));
        }
    }
    {
        const int P = S_s[0];
        for (int i = P + tid; i < 4098; i += NT) starts_s[i] = (uint16_t)SEQ;
    }
    __syncthreads();                     // b5

    // ---- G: emit this quarter; 4-lane groups, alignbit extraction; nt-stores ----
    {
        int* outp = out + (size_t)b * (MAXP * 16);
        int* outm = out + (size_t)NB * MAXP * 16 + (size_t)b * MAXP;
        const int j = tid & 3;
        #pragma unroll
        for (int it = 0; it < (MAXP / RED) / (NT / 4); ++it) {   // 8 passes
            const int p = qc * (MAXP / RED) + it * (NT / 4) + (tid >> 2);
            const int st = (int)starts_s[p];
            const int sz = (int)starts_s[p + 1] - st;            // 0..16 (0 when p>=P)
            const int base = (st >> 2) + j;
            const uint32_t sh = (uint32_t)(st & 3) * 8u;
            uint32_t lo = tok32[base], hi = tok32[base + 1];
            uint32_t pk = (uint32_t)((((uint64_t)hi << 32) | lo) >> sh);
            int rem = sz - 4 * j;
            rem = (rem < 0) ? 0 : (rem > 4 ? 4 : rem);
            pk &= (uint32_t)((1ULL << (8 * rem)) - 1ULL);
            i32x4 v = { (int)(pk & 255u), (int)((pk >> 8) & 255u),
                        (int)((pk >> 16) & 255u), (int)(pk >> 24) };
            __builtin_nontemporal_store(v, (i32x4*)outp + (size_t)p * 4 + j);
        }
        if (tid < (MAXP / RED) / 4) {    // masks: one int4 pass (256 threads)
            const int p4 = qc * (MAXP / RED) + tid * 4;
            const uint32_t* s32 = (const uint32_t*)starts_s;
            uint32_t a = s32[p4 >> 1], bw = s32[(p4 >> 1) + 1];
            i32x4 mv = { (a & 0xFFFFu) < SEQ ? 1 : 0, (a >> 16) < SEQ ? 1 : 0,
                         (bw & 0xFFFFu) < SEQ ? 1 : 0, (bw >> 16) < SEQ ? 1 : 0 };
            __builtin_nontemporal_store(mv, (i32x4*)(outm + qc * (MAXP / RED)) + tid);
        }
    }
}

extern "C" void kernel_launch(void* const* d_in, const int* in_sizes, int n_in,
                              void* d_out, int out_size, void* d_ws, size_t ws_size,
                              hipStream_t stream) {
    const int* tokens = (const int*)d_in[0];
    int* out = (int*)d_out;
    ep_fused<<<dim3(NB * RED), dim3(NT), 0, stream>>>(tokens, out);
}

// Round 17
// 19.014 us; speedup vs baseline: 1.0921x; 1.0921x over previous
//
#include <hip/hip_runtime.h>
#include <stdint.h>

#define SEQ  8192
#define NB   128
#define MAXP 4096
#define NT   1024
#define RED  2                     // blocks per sequence (grid = 256 = 1 block/CU)
#define NCH  256                   // 32-wide chunks per sequence

typedef int  i32x4 __attribute__((ext_vector_type(4)));   // native vec for nt-store

__device__ __forceinline__ bool haszero8(uint64_t v) {
    return ((v - 0x0101010101010101ULL) & ~v & 0x8080808080808080ULL) != 0ULL;
}
__device__ __forceinline__ bool distinct8(uint64_t w) {
    uint64_t r1 = (w >> 8)  | (w << 56);
    uint64_t r2 = (w >> 16) | (w << 48);
    uint64_t r3 = (w >> 24) | (w << 40);
    uint64_t r4 = (w >> 32) | (w << 32);
    return !(haszero8(w ^ r1) | haszero8(w ^ r2) | haszero8(w ^ r3) | haszero8(w ^ r4));
}
__device__ __forceinline__ uint32_t pack4(int4 v) {
    return (uint32_t)(v.x & 255) | ((uint32_t)(v.y & 255) << 8) |
           ((uint32_t)(v.z & 255) << 16) | ((uint32_t)(v.w & 255) << 24);
}
__device__ __forceinline__ uint32_t bsel16(uint4 f, uint32_t b) {
    uint32_t w01 = (b & 4u) ? f.y : f.x;
    uint32_t w23 = (b & 4u) ? f.w : f.z;
    uint32_t w   = (b & 8u) ? w23 : w01;
    return (w >> ((b & 3u) << 3)) & 255u;
}
// byte pack: {a.b2,a.b0,b.b2,b.b0} -> one word (exit-byte table)
__device__ __forceinline__ uint32_t packexit(uint32_t pa, uint32_t pb) {
#if __has_builtin(__builtin_amdgcn_perm)
    return __builtin_amdgcn_perm(pb, pa, 0x06040200u);
#else
    return (pa & 0xFFu) | (((pa >> 16) & 0xFFu) << 8) |
           ((pb & 0xFFu) << 16) | (((pb >> 16) & 0xFFu) << 24);
#endif
}
// r.byte[i] = g.byte[f.byte[i]]  (byte values in [0,16)) -- proven rounds 5-15
__device__ __forceinline__ uint4 comp16(uint4 g, uint4 f) {
    uint4 r;
#if __has_builtin(__builtin_amdgcn_perm)
    #define C16W(fw, out) do { \
        uint32_t sel = (fw) & 0x07070707u; \
        uint32_t lo = __builtin_amdgcn_perm(g.y, g.x, sel); \
        uint32_t hi = __builtin_amdgcn_perm(g.w, g.z, sel); \
        uint32_t m = ((fw) & 0x08080808u) >> 3; m = (m << 8) - m; \
        out = (lo & ~m) | (hi & m); } while (0)
    C16W(f.x, r.x); C16W(f.y, r.y); C16W(f.z, r.z); C16W(f.w, r.w);
    #undef C16W
#else
    #define C16B(fw, out) do { uint32_t o = 0; \
        o |= bsel16(g, (fw) & 15u); \
        o |= bsel16(g, ((fw) >> 8) & 15u) << 8; \
        o |= bsel16(g, ((fw) >> 16) & 15u) << 16; \
        o |= bsel16(g, ((fw) >> 24) & 15u) << 24; \
        out = o; } while (0)
    C16B(f.x, r.x); C16B(f.y, r.y); C16B(f.z, r.z); C16B(f.w, r.w);
    #undef C16B
#endif
    return r;
}

__global__ __launch_bounds__(NT) void ep_fused(const int* __restrict__ tokens,
                                               int* __restrict__ out) {
    __shared__ uint32_t tok32[2056];     // 8192 tokens u8-packed + 32B zero pad
    __shared__ uint32_t stopb[258];
    __shared__ uint32_t st16[NCH * 9];   // per chunk: st[0..15] packed (8 words, stride 9)
    __shared__ uint32_t exitf32[NCH * 4];
    __shared__ uint8_t  entry_s[NCH];
    __shared__ uint16_t pbase_s[NCH];
    __shared__ uint16_t starts_s[4100];
    __shared__ int S_s[2];               // 0: total P

    const int bx = blockIdx.x;
    const int b = bx >> 1, qc = bx & 1;  // sequence, emission half
    const int tid = threadIdx.x;

    // ---- A: coalesced load, pack tokens to u8 (proven) ----
    {
        const int4* t4 = (const int4*)(tokens + (size_t)b * SEQ);
        #pragma unroll
        for (int k = 0; k < 2; ++k) { int g = k * NT + tid; tok32[g] = pack4(t4[g]); }
        if (tid < 8) tok32[2048 + tid] = 0u;
        if (tid < 2) stopb[256 + tid] = 0u;
    }
    __syncthreads();                     // b1

    // ---- B: stop bits, 8 windows/thread; pack 4 threads -> 1 word via shfl ----
    {
        const int base = tid * 2;
        uint64_t win = (uint64_t)tok32[base] | ((uint64_t)tok32[base + 1] << 32);
        uint32_t nx0 = tok32[base + 2], nx1 = tok32[base + 3];
        uint32_t bits = 0;
        #pragma unroll
        for (int m = 0; m < 4; ++m) {
            if (distinct8(win)) bits |= (1u << m);
            win = (win >> 8) | ((uint64_t)(nx0 & 255u) << 56);
            nx0 >>= 8;
        }
        #pragma unroll
        for (int m = 4; m < 8; ++m) {
            if (distinct8(win)) bits |= (1u << m);
            win = (win >> 8) | ((uint64_t)(nx1 & 255u) << 56);
            nx1 >>= 8;
        }
        if (tid == NT - 1) bits &= 0x1u;             // only j=8184 valid on tail thread
        uint32_t a = bits | ((uint32_t)__shfl_xor((int)bits, 1) << 8);
        uint32_t w32 = a | ((uint32_t)__shfl_xor((int)a, 2) << 16);
        if ((tid & 3) == 0) stopb[tid >> 2] = w32;
    }
    __syncthreads();                     // b2

    // ---- T: per-chunk backward DP, register sliding window (proven R12) ----
    if (tid < NCH) {
        const int c = tid;
        const uint64_t W = (uint64_t)stopb[c] | ((uint64_t)stopb[c + 1] << 32);
        const int gb = c * 32;
        uint32_t p0 = 0, p1 = 0, p2 = 0, p3 = 0, p4 = 0, p5 = 0, p6 = 0, p7 = 0;
        #pragma unroll
        for (int rel = 31; rel >= 0; --rel) {
            uint32_t win14 = (uint32_t)(W >> (rel + 2)) & 0x3FFFu;
            int sz = win14 ? (2 + __builtin_ctz(win14)) : min(16, SEQ - (gb + rel));
            int nxt = rel + sz;
            uint32_t stv;
            if (nxt >= 32) {
                stv = (uint32_t)(nxt - 32) | 0x100u;
            } else {
                int s = sz - 1;
                uint32_t q01 = (s & 2) ? p1 : p0;
                uint32_t q23 = (s & 2) ? p3 : p2;
                uint32_t q45 = (s & 2) ? p5 : p4;
                uint32_t q67 = (s & 2) ? p7 : p6;
                uint32_t qa  = (s & 4) ? q23 : q01;
                uint32_t qb  = (s & 4) ? q67 : q45;
                uint32_t q   = (s & 8) ? qb : qa;
                uint32_t sel = (s & 1) ? (q >> 16) : (q & 0xFFFFu);
                stv = sel + 0x100u;
            }
            p7 = (p7 << 16) | (p6 >> 16);
            p6 = (p6 << 16) | (p5 >> 16);
            p5 = (p5 << 16) | (p4 >> 16);
            p4 = (p4 << 16) | (p3 >> 16);
            p3 = (p3 << 16) | (p2 >> 16);
            p2 = (p2 << 16) | (p1 >> 16);
            p1 = (p1 << 16) | (p0 >> 16);
            p0 = (p0 << 16) | stv;
        }
        uint32_t* st = st16 + c * 9;
        st[0] = p0; st[1] = p1; st[2] = p2; st[3] = p3;
        st[4] = p4; st[5] = p5; st[6] = p6; st[7] = p7;
        exitf32[c * 4 + 0] = packexit(p0, p1);
        exitf32[c * 4 + 1] = packexit(p2, p3);
        exitf32[c * 4 + 2] = packexit(p4, p5);
        exitf32[c * 4 + 3] = packexit(p6, p7);
    }
    __syncthreads();                     // b3

    // ---- S: wave-0 mega-phase: fn scan -> entries, counts, pbases, P (proven) ----
    if (tid < 64) {
        const uint4* xf4 = (const uint4*)exitf32;
        uint4 f0 = xf4[tid * 4], f1 = xf4[tid * 4 + 1],
              f2 = xf4[tid * 4 + 2], f3 = xf4[tid * 4 + 3];
        uint4 g = comp16(f1, f0);
        g = comp16(f2, g);
        g = comp16(f3, g);
        #pragma unroll
        for (int d = 1; d < 64; d <<= 1) {
            uint4 o;
            o.x = (uint32_t)__shfl_up((int)g.x, d);
            o.y = (uint32_t)__shfl_up((int)g.y, d);
            o.z = (uint32_t)__shfl_up((int)g.z, d);
            o.w = (uint32_t)__shfl_up((int)g.w, d);
            if (tid >= d) g = comp16(g, o);
        }
        uint4 E;
        E.x = (uint32_t)__shfl_up((int)g.x, 1);
        E.y = (uint32_t)__shfl_up((int)g.y, 1);
        E.z = (uint32_t)__shfl_up((int)g.z, 1);
        E.w = (uint32_t)__shfl_up((int)g.w, 1);
        if (tid == 0) E = make_uint4(0x03020100u, 0x07060504u, 0x0B0A0908u, 0x0F0E0D0Cu);
        uint32_t e0 = E.x & 255u;
        uint32_t e1 = bsel16(f0, e0);
        uint32_t e2 = bsel16(f1, e1);
        uint32_t e3 = bsel16(f2, e2);
        entry_s[tid * 4 + 0] = (uint8_t)e0;
        entry_s[tid * 4 + 1] = (uint8_t)e1;
        entry_s[tid * 4 + 2] = (uint8_t)e2;
        entry_s[tid * 4 + 3] = (uint8_t)e3;
        uint32_t w0 = st16[(tid * 4 + 0) * 9 + (e0 >> 1)];
        uint32_t w1 = st16[(tid * 4 + 1) * 9 + (e1 >> 1)];
        uint32_t w2 = st16[(tid * 4 + 2) * 9 + (e2 >> 1)];
        uint32_t w3 = st16[(tid * 4 + 3) * 9 + (e3 >> 1)];
        int c0 = (int)(((w0 >> ((e0 & 1) * 16)) & 0xFFFFu) >> 8);
        int c1 = (int)(((w1 >> ((e1 & 1) * 16)) & 0xFFFFu) >> 8);
        int c2 = (int)(((w2 >> ((e2 & 1) * 16)) & 0xFFFFu) >> 8);
        int c3 = (int)(((w3 >> ((e3 & 1) * 16)) & 0xFFFFu) >> 8);
        int s = c0 + c1 + c2 + c3;
        int incl = s;
        #pragma unroll
        for (int d = 1; d < 64; d <<= 1) { int o = __shfl_up(incl, d); if (tid >= d) incl += o; }
        int excl = incl - s;
        pbase_s[tid * 4 + 0] = (uint16_t)excl;
        pbase_s[tid * 4 + 1] = (uint16_t)(excl + c0);
        pbase_s[tid * 4 + 2] = (uint16_t)(excl + c0 + c1);
        pbase_s[tid * 4 + 3] = (uint16_t)(excl + c0 + c1 + c2);
        if (tid == 63) S_s[0] = incl;    // total P
    }
    __syncthreads();                     // b4

    // ---- X: expand chunks via register walk + sentinel fill ----
    if (tid < NCH) {
        const int c = tid;
        const uint64_t W = (uint64_t)stopb[c] | ((uint64_t)stopb[c + 1] << 32);
        const int gb = c * 32;
        int pb = (int)pbase_s[c];
        int rel = (int)entry_s[c];
        while (rel < 32) {
            starts_s[pb++] = (uint16_t)(gb + rel);
            uint32_t win14 = (uint32_t)(W >> (rel + 2)) & 0x3FFFu;
            rel += win14 ? (2 + __builtin_ctz(win14)) : min(16, SEQ - (gb + rel));
        }
    }
    {
        const int P = S_s[0];
        for (int i = P + tid; i < 4098; i += NT) starts_s[i] = (uint16_t)SEQ;
    }
    __syncthreads();                     // b5

    // ---- G: emit this half; 4-lane groups, alignbit extraction; nt-stores ----
    {
        int* outp = out + (size_t)b * (MAXP * 16);
        int* outm = out + (size_t)NB * MAXP * 16 + (size_t)b * MAXP;
        const int j = tid & 3;
        #pragma unroll
        for (int it = 0; it < (MAXP / RED) / (NT / 4); ++it) {   // 8 passes
            const int p = qc * (MAXP / RED) + it * (NT / 4) + (tid >> 2);
            const int st = (int)starts_s[p];
            const int sz = (int)starts_s[p + 1] - st;            // 0..16 (0 when p>=P)
            const int base = (st >> 2) + j;
            const uint32_t sh = (uint32_t)(st & 3) * 8u;
            uint32_t lo = tok32[base], hi = tok32[base + 1];
            uint32_t pk = (uint32_t)((((uint64_t)hi << 32) | lo) >> sh);
            int rem = sz - 4 * j;
            rem = (rem < 0) ? 0 : (rem > 4 ? 4 : rem);
            pk &= (uint32_t)((1ULL << (8 * rem)) - 1ULL);
            i32x4 v = { (int)(pk & 255u), (int)((pk >> 8) & 255u),
                        (int)((pk >> 16) & 255u), (int)(pk >> 24) };
            __builtin_nontemporal_store(v, (i32x4*)outp + (size_t)p * 4 + j);
        }
        if (tid < (MAXP / RED) / 4) {    // masks: one int4 pass (512 threads)
            const int p4 = qc * (MAXP / RED) + tid * 4;
            const uint32_t* s32 = (const uint32_t*)starts_s;
            uint32_t a = s32[p4 >> 1], bw = s32[(p4 >> 1) + 1];
            i32x4 mv = { (a & 0xFFFFu) < SEQ ? 1 : 0, (a >> 16) < SEQ ? 1 : 0,
                         (bw & 0xFFFFu) < SEQ ? 1 : 0, (bw >> 16) < SEQ ? 1 : 0 };
            __builtin_nontemporal_store(mv, (i32x4*)(outm + qc * (MAXP / RED)) + tid);
        }
    }
}

extern "C" void kernel_launch(void* const* d_in, const int* in_sizes, int n_in,
                              void* d_out, int out_size, void* d_ws, size_t ws_size,
                              hipStream_t stream) {
    const int* tokens = (const int*)d_in[0];
    int* out = (int*)d_out;
    ep_fused<<<dim3(NB * RED), dim3(NT), 0, stream>>>(tokens, out);
}